// Round 14
// baseline (575.388 us; speedup 1.0000x reference)
//
#include <hip/hip_runtime.h>

// SMPL forward: B=512 batches, V=6890 verts, NB=10 shape dims, NJ=24 joints, 9 extra joints.
// Output fp32 (B, V+33, 3).
//
// Round-14 structure (1 memset + 2 kernels):
//   fused_kernel (512x256, PLAIN launch) — phase T (transpose, blocks 0-26)
//       -> spin grid-barrier -> phase P (pre, block-roles 0-407)
//       -> spin grid-barrier -> phase J (joints, all 512 blocks).
//       Phase bodies are the r10 kernels verbatim -> bitwise-same math.
//   lbs_kernel (27x128) — r10 version verbatim (51.8-52.0 µs measured).
//
// Why not hipLaunchCooperativeKernel: r13's coop version hit "container
// failed twice" — indistinguishable from the r1/r9 infra flakes, but coop
// launch under graph capture is a plausible deterministic abort. This spin
// barrier uses only constructs already proven in this harness (plain
// launches, hipMemsetAsync under capture, device-scope atomics).
// Residency guarantee for the barrier: 512 blocks / 256 CUs = 2 blocks/CU,
// needs VGPR<=256 (phases measure ~48-64) and LDS ~6.6KB/block — all
// blocks co-resident, no deadlock. Release/acquire per G16: threadfence +
// device-scope atomic arrive + acquire spin + threadfence.
//
// lbs elimination tree (6 variants, do not revisit): s_load/BPB4 = 52.0 <<
// BPB1 57 < LDS-broadcast 114 < VPT2-stream 173 < VPT2-pin 178 <
// vector-flat 203. Never set the 2nd __launch_bounds__ arg (spilled r2/r4).
// LDS layouts need bank arithmetic first (r11: stride-24 = 16-way conflict).

#define BATCH 512
#define NV 6890
#define NBD 10
#define NJ 24
#define NEXTRA 9
#define NOUT (NV + NJ + NEXTRA)   // 6923
#define VBLK ((NV + 255) / 256)   // 27
#define BPB 4                     // batches per block in LBS kernel
#define PCHUNK 8                  // jtjs V-chunks (partial sums)
#define PCLEN ((NV + PCHUNK - 1) / PCHUNK)  // 862
#define EPN 34                    // per-(e,j) operator floats: 3 P0 + 30 PL + 1 W
#define PREB ((PCHUNK + NEXTRA) * NJ)       // 408 pre block-roles
#define GRIDB 512                 // fused kernel grid (2 blocks/CU -> co-resident)

__constant__ int c_par[NJ] = {-1,0,0,0,1,2,3,4,5,6,7,8,9,9,9,12,13,14,16,17,18,19,20,21};
// kinematic depth of each joint (parent of depth-k joint has depth k-1)
__constant__ int c_dep[NJ] = {0,1,1,1,2,2,2,3,3,3,4,4,4,4,4,5,5,5,6,6,7,7,8,8};

// Device-scope grid barrier (one-shot counter per use; counters zeroed by a
// hipMemsetAsync node before each launch). All GRIDB blocks are co-resident
// by construction (see header), so the spin cannot deadlock.
__device__ __forceinline__ void grid_barrier(int* cnt)
{
    __syncthreads();                              // block done with prior phase
    if (threadIdx.x == 0) {
        __threadfence();                          // release prior global writes
        __hip_atomic_fetch_add(cnt, 1, __ATOMIC_ACQ_REL, __HIP_MEMORY_SCOPE_AGENT);
        while (__hip_atomic_load(cnt, __ATOMIC_ACQUIRE, __HIP_MEMORY_SCOPE_AGENT) < GRIDB)
            __builtin_amdgcn_s_sleep(2);
    }
    __syncthreads();                              // block waits on lane 0's spin
    __threadfence();                              // acquire propagation for all threads
}

// ---------------------------------------------------------------------------
// Fused batch-independent + per-batch-joints kernel. grid 512 x block 256.
// ---------------------------------------------------------------------------
__global__ __launch_bounds__(256) void fused_kernel(
    const float* __restrict__ jreg,
    const float* __restrict__ jre,
    const float* __restrict__ lbsw,
    const float* __restrict__ smpl_t,
    const float* __restrict__ smil_t,
    const float* __restrict__ sdirs,
    const float* __restrict__ msc,
    const float* __restrict__ betas,
    const float* __restrict__ body_pose,
    const float* __restrict__ glob_or,
    const float* __restrict__ transl,
    float* __restrict__ vtT,
    float* __restrict__ sdT,
    float* __restrict__ lbswT,
    float* __restrict__ jtjs_part,
    float* __restrict__ epre,
    float* __restrict__ wsA,
    float* __restrict__ out,
    int* __restrict__ bar)
{
    const int bid = blockIdx.x;
    const int tid = threadIdx.x;

    __shared__ float red[4][EPN];        // phase P reduction
    __shared__ float sJ[NJ][3];          // phase J
    __shared__ float mats[NJ][12];
    __shared__ float chain[NJ][12];
    __shared__ float sbeta[NBD + 1];
    __shared__ float sS[NEXTRA][NJ][3];
    __shared__ float sW[NEXTRA][NJ];

    // ======== phase T: operand transpose (blocks 0..26) ========
    if (bid < VBLK) {
        const int v = bid * 256 + tid;
        if (v < NV) {
            const float s = msc[0];
#pragma unroll
            for (int k = 0; k < 3; ++k)
                vtT[k * NV + v] = s * smpl_t[v * 3 + k] + (1.f - s) * smil_t[v * 3 + k];
            const float2* sd2 = (const float2*)(sdirs + (size_t)v * 30);
#pragma unroll
            for (int i = 0; i < 15; ++i) {
                float2 x = sd2[i];
                sdT[(2 * i) * NV + v]     = x.x;
                sdT[(2 * i + 1) * NV + v] = x.y;
            }
            const float4* w4 = (const float4*)(lbsw + (size_t)v * NJ);
#pragma unroll
            for (int i = 0; i < 6; ++i) {
                float4 x = w4[i];
                lbswT[(4 * i) * NV + v]     = x.x;
                lbswT[(4 * i + 1) * NV + v] = x.y;
                lbswT[(4 * i + 2) * NV + v] = x.z;
                lbswT[(4 * i + 3) * NV + v] = x.w;
            }
        }
    }
    grid_barrier(&bar[0]);

    // ======== phase P: pre (block-roles 0..407) ========
    if (bid < PREB) {
        const int x = bid % (PCHUNK + NEXTRA);
        const int j = bid / (PCHUNK + NEXTRA);
        const int lane = tid & 63, wv = tid >> 6;

        if (x < PCHUNK) {
            // role 1: jtjs partial over chunk
            const int c = x;
            const int vbeg = c * PCLEN;
            const int vend_ = (vbeg + PCLEN < NV) ? vbeg + PCLEN : NV;

            float acc[33];
#pragma unroll
            for (int i = 0; i < 33; ++i) acc[i] = 0.f;

            for (int v = vbeg + tid; v < vend_; v += 256) {
                const float w = jreg[j * NV + v];
#pragma unroll
                for (int k = 0; k < 3; ++k) acc[k] = fmaf(w, vtT[k * NV + v], acc[k]);
#pragma unroll
                for (int i = 0; i < 30; ++i) acc[3 + i] = fmaf(w, sdT[i * NV + v], acc[3 + i]);
            }

#pragma unroll
            for (int i = 0; i < 33; ++i) {
                float xx = acc[i];
                for (int off = 32; off; off >>= 1) xx += __shfl_xor(xx, off, 64);
                acc[i] = xx;
            }
            if (lane == 0) {
#pragma unroll
                for (int i = 0; i < 33; ++i) red[wv][i] = acc[i];
            }
            __syncthreads();
            if (tid < 33) {
                jtjs_part[(c * NJ + j) * 33 + tid] =
                    red[0][tid] + red[1][tid] + red[2][tid] + red[3][tid];
            }
        } else {
            // role 2: linearized extra operators for extra-joint e
            const int e = x - PCHUNK;

            float acc[EPN];
#pragma unroll
            for (int i = 0; i < EPN; ++i) acc[i] = 0.f;

            for (int v = tid; v < NV; v += 256) {
                const float u = jre[e * NV + v] * lbswT[j * NV + v];
                acc[33] += u;
#pragma unroll
                for (int k = 0; k < 3; ++k) acc[k] = fmaf(u, vtT[k * NV + v], acc[k]);
#pragma unroll
                for (int i = 0; i < 30; ++i) acc[3 + i] = fmaf(u, sdT[i * NV + v], acc[3 + i]);
            }

#pragma unroll
            for (int i = 0; i < EPN; ++i) {
                float xx = acc[i];
                for (int off = 32; off; off >>= 1) xx += __shfl_xor(xx, off, 64);
                acc[i] = xx;
            }
            if (lane == 0) {
#pragma unroll
                for (int i = 0; i < EPN; ++i) red[wv][i] = acc[i];
            }
            __syncthreads();
            if (tid < EPN) {
                epre[(e * NJ + j) * EPN + tid] =
                    red[0][tid] + red[1][tid] + red[2][tid] + red[3][tid];
            }
        }
    }
    grid_barrier(&bar[1]);

    // ======== phase J: joints for batch b = bid (all 512 blocks) ========
    {
        const int b = bid;
        const int j = tid;

        if (tid < NBD + 1) sbeta[tid] = betas[b * (NBD + 1) + tid];
        __syncthreads();

        if (j < NJ) {
            float jt[33];
#pragma unroll
            for (int i = 0; i < 33; ++i) jt[i] = 0.f;
            for (int c = 0; c < PCHUNK; ++c) {
#pragma unroll
                for (int i = 0; i < 33; ++i) jt[i] += jtjs_part[(c * NJ + j) * 33 + i];
            }

            const float beta0 = sbeta[0];
#pragma unroll
            for (int k = 0; k < 3; ++k) {
                float a = jt[k];
#pragma unroll
                for (int l = 0; l < NBD; ++l) a = fmaf(sbeta[1 + l], jt[3 + k * 10 + l], a);
                sJ[j][k] = a * beta0;
            }
            // Rodrigues. angle uses rvec+1e-8 per-component; axis uses raw rvec.
            float rx, ry, rz;
            if (j == 0) {
                rx = glob_or[b * 3 + 0]; ry = glob_or[b * 3 + 1]; rz = glob_or[b * 3 + 2];
            } else {
                rx = body_pose[b * 69 + (j - 1) * 3 + 0];
                ry = body_pose[b * 69 + (j - 1) * 3 + 1];
                rz = body_pose[b * 69 + (j - 1) * 3 + 2];
            }
            float ex = rx + 1e-8f, ey = ry + 1e-8f, ez = rz + 1e-8f;
            float ang = sqrtf(ex * ex + ey * ey + ez * ez);
            float inv = 1.f / ang;
            float ax = rx * inv, ay = ry * inv, az = rz * inv;
            float c = cosf(ang), s = sinf(ang), t = 1.f - c;
            mats[j][0]  = 1.f + t * (-(ay * ay + az * az));
            mats[j][1]  = -s * az + t * (ax * ay);
            mats[j][2]  =  s * ay + t * (ax * az);
            mats[j][4]  =  s * az + t * (ax * ay);
            mats[j][5]  = 1.f + t * (-(ax * ax + az * az));
            mats[j][6]  = -s * ax + t * (ay * az);
            mats[j][8]  = -s * ay + t * (ax * az);
            mats[j][9]  =  s * ax + t * (ay * az);
            mats[j][10] = 1.f + t * (-(ax * ax + ay * ay));
        }
        __syncthreads();
        if (j < NJ) {
            const int p = c_par[j];
            float t0 = sJ[j][0], t1 = sJ[j][1], t2 = sJ[j][2];
            if (p >= 0) { t0 -= sJ[p][0]; t1 -= sJ[p][1]; t2 -= sJ[p][2]; }
            mats[j][3] = t0; mats[j][7] = t1; mats[j][11] = t2;
        }
        __syncthreads();
        if (j == 0) {
#pragma unroll
            for (int k = 0; k < 12; ++k) chain[0][k] = mats[0][k];
        }
        __syncthreads();
        for (int lev = 1; lev <= 8; ++lev) {
            if (j < NJ && c_dep[j] == lev) {
                const int p = c_par[j];
                float r_[12];
#pragma unroll
                for (int r = 0; r < 3; ++r) {
#pragma unroll
                    for (int col = 0; col < 4; ++col) {
                        float acc = (col == 3) ? chain[p][r * 4 + 3] : 0.f;
#pragma unroll
                        for (int q = 0; q < 3; ++q) acc = fmaf(chain[p][r * 4 + q], mats[j][q * 4 + col], acc);
                        r_[r * 4 + col] = acc;
                    }
                }
#pragma unroll
                for (int k = 0; k < 12; ++k) chain[j][k] = r_[k];
            }
            __syncthreads();
        }
        if (j < NJ) {
            float A[12];
#pragma unroll
            for (int k = 0; k < 12; ++k) A[k] = chain[j][k];
            const float c0 = A[3], c1 = A[7], c2 = A[11];
            const float j0 = sJ[j][0], j1 = sJ[j][1], j2 = sJ[j][2];
            A[3]  = c0 - (A[0] * j0 + A[1] * j1 + A[2]  * j2);
            A[7]  = c1 - (A[4] * j0 + A[5] * j1 + A[6]  * j2);
            A[11] = c2 - (A[8] * j0 + A[9] * j1 + A[10] * j2);
#pragma unroll
            for (int k = 0; k < 12; ++k) wsA[((size_t)b * NJ + j) * 12 + k] = A[k];
#pragma unroll
            for (int k = 0; k < 12; ++k) mats[j][k] = A[k];   // stash corrected A
            const float tx = transl[b * 3 + 0], ty = transl[b * 3 + 1], tz = transl[b * 3 + 2];
            const size_t o = ((size_t)b * NOUT + NV + j) * 3;
            out[o + 0] = c0 + tx; out[o + 1] = c1 + ty; out[o + 2] = c2 + tz;
        }

        // extra joints: per-batch contraction of the linearized operators
        for (int p = tid; p < NEXTRA * NJ; p += 256) {
            const int e  = p / NJ;
            const int jj = p - e * NJ;
            const float* ep = epre + p * EPN;
#pragma unroll
            for (int cc = 0; cc < 3; ++cc) {
                float a = ep[cc];
#pragma unroll
                for (int l = 0; l < NBD; ++l) a = fmaf(sbeta[1 + l], ep[3 + cc * 10 + l], a);
                sS[e][jj][cc] = a * sbeta[0];
            }
            sW[e][jj] = ep[33];
        }
        __syncthreads();
        if (tid < 3 * NEXTRA) {
            const int e = tid / 3;
            const int k = tid - e * 3;
            float acc = 0.f;
#pragma unroll 4
            for (int jj = 0; jj < NJ; ++jj) {
                acc = fmaf(mats[jj][k * 4 + 0], sS[e][jj][0], acc);
                acc = fmaf(mats[jj][k * 4 + 1], sS[e][jj][1], acc);
                acc = fmaf(mats[jj][k * 4 + 2], sS[e][jj][2], acc);
                acc = fmaf(mats[jj][k * 4 + 3], sW[e][jj],    acc);
            }
            out[((size_t)b * NOUT + NV + NJ) * 3 + tid] = acc + transl[b * 3 + k];
        }
    }
}

// ---------------------------------------------------------------------------
// Kernel C: LBS skinning — r10 version VERBATIM (51.8-52.0 µs, VGPR 44).
// Round-0 body, BPB=4, scalar s_load A path, wave-staggered batch order.
// ---------------------------------------------------------------------------
__global__ __launch_bounds__(256) void lbs_kernel(
    const float* __restrict__ betas,
    const float* __restrict__ transl,
    const float* __restrict__ msc,
    const float* __restrict__ smpl_t,
    const float* __restrict__ smil_t,
    const float* __restrict__ sdirs,
    const float* __restrict__ lbsw,
    const float* __restrict__ wsA,
    float* __restrict__ out)
{
    const int rot = __builtin_amdgcn_readfirstlane((int)(threadIdx.x >> 6) + (int)blockIdx.x);

    const int v = blockIdx.x * 256 + threadIdx.x;
    const bool valid = v < NV;
    const int vc = valid ? v : NV - 1;
    const int b0 = blockIdx.y * BPB;
    const float s = msc[0];

    float vt[3];
#pragma unroll
    for (int k = 0; k < 3; ++k)
        vt[k] = s * smpl_t[vc * 3 + k] + (1.f - s) * smil_t[vc * 3 + k];

    float sd[30];
    {
        const float2* sd2 = (const float2*)(sdirs + (size_t)vc * 30);
#pragma unroll
        for (int i = 0; i < 15; ++i) { float2 x = sd2[i]; sd[2 * i] = x.x; sd[2 * i + 1] = x.y; }
    }
    float w[NJ];
    {
        const float4* w4 = (const float4*)(lbsw + (size_t)vc * NJ);
#pragma unroll
        for (int i = 0; i < 6; ++i) {
            float4 x = w4[i];
            w[4 * i] = x.x; w[4 * i + 1] = x.y; w[4 * i + 2] = x.z; w[4 * i + 3] = x.w;
        }
    }

#pragma unroll
    for (int bb = 0; bb < BPB; ++bb) {
        const int b = b0 + ((bb + rot) & (BPB - 1));
        const float* __restrict__ Bb = betas + b * (NBD + 1);   // uniform
        const float* __restrict__ Ab = wsA + (size_t)b * NJ * 12; // uniform

        float vs[3];
#pragma unroll
        for (int k = 0; k < 3; ++k) {
            float a = vt[k];
#pragma unroll
            for (int l = 0; l < NBD; ++l) a = fmaf(Bb[1 + l], sd[k * 10 + l], a);
            vs[k] = a * Bb[0];
        }

        float T[12];
#pragma unroll
        for (int k = 0; k < 12; ++k) T[k] = 0.f;
#pragma unroll 4
        for (int jj = 0; jj < NJ; ++jj) {
            const float ww = w[jj];
#pragma unroll
            for (int k = 0; k < 12; ++k) T[k] = fmaf(ww, Ab[jj * 12 + k], T[k]);
        }

        if (valid) {
            const float tx = transl[b * 3 + 0], ty = transl[b * 3 + 1], tz = transl[b * 3 + 2];
            const size_t o = ((size_t)b * NOUT + v) * 3;
            out[o + 0] = fmaf(T[0], vs[0], fmaf(T[1], vs[1], fmaf(T[2],  vs[2], T[3])))  + tx;
            out[o + 1] = fmaf(T[4], vs[0], fmaf(T[5], vs[1], fmaf(T[6],  vs[2], T[7])))  + ty;
            out[o + 2] = fmaf(T[8], vs[0], fmaf(T[9], vs[1], fmaf(T[10], vs[2], T[11]))) + tz;
        }
    }
}

// ---------------------------------------------------------------------------
extern "C" void kernel_launch(void* const* d_in, const int* in_sizes, int n_in,
                              void* d_out, int out_size, void* d_ws, size_t ws_size,
                              hipStream_t stream) {
    const float* betas     = (const float*)d_in[0];
    const float* body_pose = (const float*)d_in[1];
    const float* glob_or   = (const float*)d_in[2];
    const float* transl    = (const float*)d_in[3];
    const float* msc       = (const float*)d_in[4];
    const float* smpl_t    = (const float*)d_in[5];
    const float* smil_t    = (const float*)d_in[6];
    const float* sdirs     = (const float*)d_in[7];
    const float* jreg      = (const float*)d_in[8];
    const float* lbsw      = (const float*)d_in[9];
    const float* jre       = (const float*)d_in[10];
    // d_in[11] = parents (hard-coded in c_par)

    float* out  = (float*)d_out;
    float* ws   = (float*)d_ws;
    float* wsA       = ws;                               // BATCH*NJ*12 = 147456 floats
    float* jtjs_part = wsA + (size_t)BATCH * NJ * 12;    // PCHUNK*NJ*33 = 6336
    float* epre      = jtjs_part + PCHUNK * NJ * 33;     // NEXTRA*NJ*34 = 7344
    float* vtT       = epre + NEXTRA * NJ * EPN;         // 3*NV  = 20670
    float* sdT       = vtT + 3 * NV;                     // 30*NV = 206700
    float* lbswT     = sdT + 30 * NV;                    // 24*NV = 165360
    int*   bar       = (int*)(lbswT + 24 * NV);          // 2 ints (barrier counters)

    // zero the one-shot barrier counters (ws is poisoned before each call)
    hipMemsetAsync(bar, 0, 2 * sizeof(int), stream);

    fused_kernel<<<GRIDB, 256, 0, stream>>>(
        jreg, jre, lbsw, smpl_t, smil_t, sdirs, msc,
        betas, body_pose, glob_or, transl,
        vtT, sdT, lbswT, jtjs_part, epre, wsA, out, bar);

    dim3 gC(VBLK, BATCH / BPB);
    lbs_kernel<<<gC, 256, 0, stream>>>(betas, transl, msc, smpl_t, smil_t, sdirs, lbsw, wsA, out);
}

// Round 15
// 173.026 us; speedup vs baseline: 3.3254x; 3.3254x over previous
//
#include <hip/hip_runtime.h>

// SMPL forward: B=512 batches, V=6890 verts, NB=10 shape dims, NJ=24 joints, 9 extra joints.
// Output fp32 (B, V+33, 3).
//
// Round-15 structure (1 memset + 4 kernels):
//   memset(jtjs)                — zero the 792-float atomic accumulator.
//   transpose_kernel (27x3)    — coalesced-operand build, 3-way split for 3x
//                                 wave count (was 27 blocks, latency-bound).
//   pre_kernel     (17x24)      — jtjs via atomicAdd (FINAL values; joints no
//                                 longer re-sums 8 partials x 512 blocks) +
//                                 linearized extra operators (epre).
//   joints_kernel  (512x64)     — Rodrigues + chain + A + 27 extra outputs;
//                                 jt phase now 33 loads/lane (was 264).
//   lbs_kernel     (27x128)     — r10 VERBATIM (51.8-52.0 µs measured).
//
// r14 measurement (spin-barrier fusion, 465 µs — grid sync via device-scope
// atomics costs ~200 µs/barrier across 8 non-coherent XCD L2s; NEVER again):
// fixed harness floor ~56-58 µs (node-count-insensitive), small-kernel
// compute ~60-65 µs (latency-bound at low occupancy), lbs 52 µs. This round
// attacks the 60-65.
//
// lbs elimination tree (6 variants, do not revisit): s_load/BPB4 = 52.0 <<
// BPB1 57 < LDS-broadcast 114 < VPT2-stream 173 < VPT2-pin 178 <
// vector-flat 203. Never set the 2nd __launch_bounds__ arg (spilled r2/r4).
// LDS layouts need bank arithmetic first (r11: stride-24 = 16-way conflict).

#define BATCH 512
#define NV 6890
#define NBD 10
#define NJ 24
#define NEXTRA 9
#define NOUT (NV + NJ + NEXTRA)   // 6923
#define VBLK ((NV + 255) / 256)   // 27
#define BPB 4                     // batches per block in LBS kernel
#define PCHUNK 8                  // jtjs V-chunks
#define PCLEN ((NV + PCHUNK - 1) / PCHUNK)  // 862
#define EPN 34                    // per-(e,j) operator floats: 3 P0 + 30 PL + 1 W

__constant__ int c_par[NJ] = {-1,0,0,0,1,2,3,4,5,6,7,8,9,9,9,12,13,14,16,17,18,19,20,21};
// kinematic depth of each joint (parent of depth-k joint has depth k-1)
__constant__ int c_dep[NJ] = {0,1,1,1,2,2,2,3,3,3,4,4,4,4,4,5,5,5,6,6,7,7,8,8};

// ---------------------------------------------------------------------------
// Kernel T: one-time operand transpose, 3-way split for wave count.
// part 0: vtT (blend folded) + sdT rows 0..13
// part 1: sdT rows 14..29
// part 2: lbswT
// ---------------------------------------------------------------------------
__global__ __launch_bounds__(256) void transpose_kernel(
    const float* __restrict__ smpl_t,
    const float* __restrict__ smil_t,
    const float* __restrict__ sdirs,
    const float* __restrict__ lbsw,
    const float* __restrict__ msc,
    float* __restrict__ vtT,
    float* __restrict__ sdT,
    float* __restrict__ lbswT)
{
    const int v = blockIdx.x * 256 + threadIdx.x;
    if (v >= NV) return;
    const int part = blockIdx.y;

    if (part == 0) {
        const float s = msc[0];
#pragma unroll
        for (int k = 0; k < 3; ++k)
            vtT[k * NV + v] = s * smpl_t[v * 3 + k] + (1.f - s) * smil_t[v * 3 + k];
        const float2* sd2 = (const float2*)(sdirs + (size_t)v * 30);
#pragma unroll
        for (int i = 0; i < 7; ++i) {
            float2 x = sd2[i];
            sdT[(2 * i) * NV + v]     = x.x;
            sdT[(2 * i + 1) * NV + v] = x.y;
        }
    } else if (part == 1) {
        const float2* sd2 = (const float2*)(sdirs + (size_t)v * 30);
#pragma unroll
        for (int i = 7; i < 15; ++i) {
            float2 x = sd2[i];
            sdT[(2 * i) * NV + v]     = x.x;
            sdT[(2 * i + 1) * NV + v] = x.y;
        }
    } else {
        const float4* w4 = (const float4*)(lbsw + (size_t)v * NJ);
#pragma unroll
        for (int i = 0; i < 6; ++i) {
            float4 x = w4[i];
            lbswT[(4 * i) * NV + v]     = x.x;
            lbswT[(4 * i + 1) * NV + v] = x.y;
            lbswT[(4 * i + 2) * NV + v] = x.z;
            lbswT[(4 * i + 3) * NV + v] = x.w;
        }
    }
}

// ---------------------------------------------------------------------------
// Kernel A (fused): batch-independent precompute. grid (PCHUNK+NEXTRA, NJ)
//  = (17, 24) = 408 blocks, block 256. All loads coalesced via vtT/sdT/lbswT.
// Role 1 (blockIdx.x < PCHUNK): jtjs partial over V-chunk c for joint j,
//   atomicAdd'ed into the memset-zeroed FINAL jtjs[24][33] (r0-proven).
// Role 2 (blockIdx.x >= PCHUNK): linearized extra operators, e = x-PCHUNK:
//   u_v = jre[e,v] * lbsw[v,j];  epre[e][j] = {sum u*vt, sum u*sd, sum u}.
// ---------------------------------------------------------------------------
__global__ __launch_bounds__(256) void pre_kernel(
    const float* __restrict__ jreg,
    const float* __restrict__ jre,
    const float* __restrict__ vtT,
    const float* __restrict__ sdT,
    const float* __restrict__ lbswT,
    float* __restrict__ jtjs,
    float* __restrict__ epre)
{
    const int j = blockIdx.y;

    __shared__ float red[4][EPN];
    const int lane = threadIdx.x & 63, wv = threadIdx.x >> 6;

    if (blockIdx.x < PCHUNK) {
        // ----- role 1: jtjs partial over chunk, atomic-finalized -----
        const int c = blockIdx.x;
        const int vbeg = c * PCLEN;
        const int vend_ = (vbeg + PCLEN < NV) ? vbeg + PCLEN : NV;

        float acc[33];
#pragma unroll
        for (int i = 0; i < 33; ++i) acc[i] = 0.f;

        for (int v = vbeg + threadIdx.x; v < vend_; v += 256) {
            const float w = jreg[j * NV + v];
#pragma unroll
            for (int k = 0; k < 3; ++k) acc[k] = fmaf(w, vtT[k * NV + v], acc[k]);
#pragma unroll
            for (int i = 0; i < 30; ++i) acc[3 + i] = fmaf(w, sdT[i * NV + v], acc[3 + i]);
        }

#pragma unroll
        for (int i = 0; i < 33; ++i) {
            float x = acc[i];
            for (int off = 32; off; off >>= 1) x += __shfl_xor(x, off, 64);
            acc[i] = x;
        }
        if (lane == 0) {
#pragma unroll
            for (int i = 0; i < 33; ++i) red[wv][i] = acc[i];
        }
        __syncthreads();
        if (threadIdx.x < 33) {
            atomicAdd(&jtjs[j * 33 + threadIdx.x],
                      red[0][threadIdx.x] + red[1][threadIdx.x]
                    + red[2][threadIdx.x] + red[3][threadIdx.x]);
        }
    } else {
        // ----- role 2: extra-joint operators for extra-joint e -----
        const int e = blockIdx.x - PCHUNK;

        float acc[EPN];
#pragma unroll
        for (int i = 0; i < EPN; ++i) acc[i] = 0.f;

        for (int v = threadIdx.x; v < NV; v += 256) {
            const float u = jre[e * NV + v] * lbswT[j * NV + v];
            acc[33] += u;
#pragma unroll
            for (int k = 0; k < 3; ++k) acc[k] = fmaf(u, vtT[k * NV + v], acc[k]);
#pragma unroll
            for (int i = 0; i < 30; ++i) acc[3 + i] = fmaf(u, sdT[i * NV + v], acc[3 + i]);
        }

#pragma unroll
        for (int i = 0; i < EPN; ++i) {
            float x = acc[i];
            for (int off = 32; off; off >>= 1) x += __shfl_xor(x, off, 64);
            acc[i] = x;
        }
        if (lane == 0) {
#pragma unroll
            for (int i = 0; i < EPN; ++i) red[wv][i] = acc[i];
        }
        __syncthreads();
        if (threadIdx.x < EPN) {
            epre[(e * NJ + j) * EPN + threadIdx.x] =
                red[0][threadIdx.x] + red[1][threadIdx.x]
              + red[2][threadIdx.x] + red[3][threadIdx.x];
        }
    }
}

// ---------------------------------------------------------------------------
// Kernel B: per-batch joints — Rodrigues, kinematic chain, A matrices, AND
// the 27 extra-joint outputs. grid BATCH, block 64. Lanes 0..23 own joint j.
// v15: jt phase reads the FINAL jtjs (33 loads/lane; was 8 partials = 264).
// ---------------------------------------------------------------------------
__global__ __launch_bounds__(64) void joints_kernel(
    const float* __restrict__ betas,
    const float* __restrict__ body_pose,
    const float* __restrict__ glob_or,
    const float* __restrict__ transl,
    const float* __restrict__ jtjs,
    const float* __restrict__ epre,
    float* __restrict__ wsA,
    float* __restrict__ out)
{
    const int b = blockIdx.x;
    const int j = threadIdx.x;

    __shared__ float sJ[NJ][3];       // J_shaped
    __shared__ float mats[NJ][12];    // [R | rel_t], then reused for corrected A
    __shared__ float chain[NJ][12];
    __shared__ float sbeta[NBD + 1];
    __shared__ float sS[NEXTRA][NJ][3];  // beta0*(P0 + betas·PL)
    __shared__ float sW[NEXTRA][NJ];

    if (threadIdx.x < NBD + 1) sbeta[threadIdx.x] = betas[b * (NBD + 1) + threadIdx.x];
    __syncthreads();

    if (j < NJ) {
        const float* jt = jtjs + j * 33;   // final values, 33 floats

        const float beta0 = sbeta[0];
        // J_shaped[b,j,k]
#pragma unroll
        for (int k = 0; k < 3; ++k) {
            float a = jt[k];
#pragma unroll
            for (int l = 0; l < NBD; ++l) a = fmaf(sbeta[1 + l], jt[3 + k * 10 + l], a);
            sJ[j][k] = a * beta0;
        }
        // Rodrigues. angle uses rvec+1e-8 per-component; axis uses raw rvec.
        float rx, ry, rz;
        if (j == 0) {
            rx = glob_or[b * 3 + 0]; ry = glob_or[b * 3 + 1]; rz = glob_or[b * 3 + 2];
        } else {
            rx = body_pose[b * 69 + (j - 1) * 3 + 0];
            ry = body_pose[b * 69 + (j - 1) * 3 + 1];
            rz = body_pose[b * 69 + (j - 1) * 3 + 2];
        }
        float ex = rx + 1e-8f, ey = ry + 1e-8f, ez = rz + 1e-8f;
        float ang = sqrtf(ex * ex + ey * ey + ez * ez);
        float inv = 1.f / ang;
        float ax = rx * inv, ay = ry * inv, az = rz * inv;
        float c = cosf(ang), s = sinf(ang), t = 1.f - c;
        // R = I + s*K + (1-c)*K^2
        mats[j][0]  = 1.f + t * (-(ay * ay + az * az));
        mats[j][1]  = -s * az + t * (ax * ay);
        mats[j][2]  =  s * ay + t * (ax * az);
        mats[j][4]  =  s * az + t * (ax * ay);
        mats[j][5]  = 1.f + t * (-(ax * ax + az * az));
        mats[j][6]  = -s * ax + t * (ay * az);
        mats[j][8]  = -s * ay + t * (ax * az);
        mats[j][9]  =  s * ax + t * (ay * az);
        mats[j][10] = 1.f + t * (-(ax * ax + ay * ay));
    }
    __syncthreads();
    if (j < NJ) {
        const int p = c_par[j];
        float t0 = sJ[j][0], t1 = sJ[j][1], t2 = sJ[j][2];
        if (p >= 0) { t0 -= sJ[p][0]; t1 -= sJ[p][1]; t2 -= sJ[p][2]; }
        mats[j][3] = t0; mats[j][7] = t1; mats[j][11] = t2;
    }
    __syncthreads();
    // chain compose, parallel over kinematic depth levels (max depth 8).
    if (j == 0) {
#pragma unroll
        for (int k = 0; k < 12; ++k) chain[0][k] = mats[0][k];
    }
    __syncthreads();
    for (int lev = 1; lev <= 8; ++lev) {
        if (j < NJ && c_dep[j] == lev) {
            const int p = c_par[j];
            float r_[12];
#pragma unroll
            for (int r = 0; r < 3; ++r) {
#pragma unroll
                for (int col = 0; col < 4; ++col) {
                    float acc = (col == 3) ? chain[p][r * 4 + 3] : 0.f;
#pragma unroll
                    for (int q = 0; q < 3; ++q) acc = fmaf(chain[p][r * 4 + q], mats[j][q * 4 + col], acc);
                    r_[r * 4 + col] = acc;
                }
            }
#pragma unroll
            for (int k = 0; k < 12; ++k) chain[j][k] = r_[k];
        }
        __syncthreads();
    }
    if (j < NJ) {
        float A[12];
#pragma unroll
        for (int k = 0; k < 12; ++k) A[k] = chain[j][k];
        const float c0 = A[3], c1 = A[7], c2 = A[11];
        const float j0 = sJ[j][0], j1 = sJ[j][1], j2 = sJ[j][2];
        A[3]  = c0 - (A[0] * j0 + A[1] * j1 + A[2]  * j2);
        A[7]  = c1 - (A[4] * j0 + A[5] * j1 + A[6]  * j2);
        A[11] = c2 - (A[8] * j0 + A[9] * j1 + A[10] * j2);
#pragma unroll
        for (int k = 0; k < 12; ++k) wsA[((size_t)b * NJ + j) * 12 + k] = A[k];
        // stash corrected A for the extra-joint sum (mats no longer needed)
#pragma unroll
        for (int k = 0; k < 12; ++k) mats[j][k] = A[k];
        // posed joints + transl
        const float tx = transl[b * 3 + 0], ty = transl[b * 3 + 1], tz = transl[b * 3 + 2];
        const size_t o = ((size_t)b * NOUT + NV + j) * 3;
        out[o + 0] = c0 + tx; out[o + 1] = c1 + ty; out[o + 2] = c2 + tz;
    }

    // ---- extra joints: per-batch contraction of the linearized operators ----
    for (int p = threadIdx.x; p < NEXTRA * NJ; p += 64) {
        const int e  = p / NJ;
        const int jj = p - e * NJ;
        const float* ep = epre + p * EPN;
#pragma unroll
        for (int cc = 0; cc < 3; ++cc) {
            float a = ep[cc];
#pragma unroll
            for (int l = 0; l < NBD; ++l) a = fmaf(sbeta[1 + l], ep[3 + cc * 10 + l], a);
            sS[e][jj][cc] = a * sbeta[0];
        }
        sW[e][jj] = ep[33];
    }
    __syncthreads();   // mats (corrected A) + sS + sW ready
    if (threadIdx.x < 3 * NEXTRA) {
        const int e = threadIdx.x / 3;
        const int k = threadIdx.x - e * 3;
        float acc = 0.f;
#pragma unroll 4
        for (int jj = 0; jj < NJ; ++jj) {
            acc = fmaf(mats[jj][k * 4 + 0], sS[e][jj][0], acc);
            acc = fmaf(mats[jj][k * 4 + 1], sS[e][jj][1], acc);
            acc = fmaf(mats[jj][k * 4 + 2], sS[e][jj][2], acc);
            acc = fmaf(mats[jj][k * 4 + 3], sW[e][jj],    acc);
        }
        out[((size_t)b * NOUT + NV + NJ) * 3 + threadIdx.x] = acc + transl[b * 3 + k];
    }
}

// ---------------------------------------------------------------------------
// Kernel C: LBS skinning — r10 version VERBATIM (51.8-52.0 µs, VGPR 44).
// Round-0 body, BPB=4, scalar s_load A path, wave-staggered batch order.
// ---------------------------------------------------------------------------
__global__ __launch_bounds__(256) void lbs_kernel(
    const float* __restrict__ betas,
    const float* __restrict__ transl,
    const float* __restrict__ msc,
    const float* __restrict__ smpl_t,
    const float* __restrict__ smil_t,
    const float* __restrict__ sdirs,
    const float* __restrict__ lbsw,
    const float* __restrict__ wsA,
    float* __restrict__ out)
{
    const int rot = __builtin_amdgcn_readfirstlane((int)(threadIdx.x >> 6) + (int)blockIdx.x);

    const int v = blockIdx.x * 256 + threadIdx.x;
    const bool valid = v < NV;
    const int vc = valid ? v : NV - 1;
    const int b0 = blockIdx.y * BPB;
    const float s = msc[0];

    float vt[3];
#pragma unroll
    for (int k = 0; k < 3; ++k)
        vt[k] = s * smpl_t[vc * 3 + k] + (1.f - s) * smil_t[vc * 3 + k];

    float sd[30];
    {
        const float2* sd2 = (const float2*)(sdirs + (size_t)vc * 30);
#pragma unroll
        for (int i = 0; i < 15; ++i) { float2 x = sd2[i]; sd[2 * i] = x.x; sd[2 * i + 1] = x.y; }
    }
    float w[NJ];
    {
        const float4* w4 = (const float4*)(lbsw + (size_t)vc * NJ);
#pragma unroll
        for (int i = 0; i < 6; ++i) {
            float4 x = w4[i];
            w[4 * i] = x.x; w[4 * i + 1] = x.y; w[4 * i + 2] = x.z; w[4 * i + 3] = x.w;
        }
    }

#pragma unroll
    for (int bb = 0; bb < BPB; ++bb) {
        const int b = b0 + ((bb + rot) & (BPB - 1));
        const float* __restrict__ Bb = betas + b * (NBD + 1);   // uniform
        const float* __restrict__ Ab = wsA + (size_t)b * NJ * 12; // uniform

        float vs[3];
#pragma unroll
        for (int k = 0; k < 3; ++k) {
            float a = vt[k];
#pragma unroll
            for (int l = 0; l < NBD; ++l) a = fmaf(Bb[1 + l], sd[k * 10 + l], a);
            vs[k] = a * Bb[0];
        }

        float T[12];
#pragma unroll
        for (int k = 0; k < 12; ++k) T[k] = 0.f;
#pragma unroll 4
        for (int jj = 0; jj < NJ; ++jj) {
            const float ww = w[jj];
#pragma unroll
            for (int k = 0; k < 12; ++k) T[k] = fmaf(ww, Ab[jj * 12 + k], T[k]);
        }

        if (valid) {
            const float tx = transl[b * 3 + 0], ty = transl[b * 3 + 1], tz = transl[b * 3 + 2];
            const size_t o = ((size_t)b * NOUT + v) * 3;
            out[o + 0] = fmaf(T[0], vs[0], fmaf(T[1], vs[1], fmaf(T[2],  vs[2], T[3])))  + tx;
            out[o + 1] = fmaf(T[4], vs[0], fmaf(T[5], vs[1], fmaf(T[6],  vs[2], T[7])))  + ty;
            out[o + 2] = fmaf(T[8], vs[0], fmaf(T[9], vs[1], fmaf(T[10], vs[2], T[11]))) + tz;
        }
    }
}

// ---------------------------------------------------------------------------
extern "C" void kernel_launch(void* const* d_in, const int* in_sizes, int n_in,
                              void* d_out, int out_size, void* d_ws, size_t ws_size,
                              hipStream_t stream) {
    const float* betas     = (const float*)d_in[0];
    const float* body_pose = (const float*)d_in[1];
    const float* glob_or   = (const float*)d_in[2];
    const float* transl    = (const float*)d_in[3];
    const float* msc       = (const float*)d_in[4];
    const float* smpl_t    = (const float*)d_in[5];
    const float* smil_t    = (const float*)d_in[6];
    const float* sdirs     = (const float*)d_in[7];
    const float* jreg      = (const float*)d_in[8];
    const float* lbsw      = (const float*)d_in[9];
    const float* jre       = (const float*)d_in[10];
    // d_in[11] = parents (hard-coded in c_par)

    float* out  = (float*)d_out;
    float* ws   = (float*)d_ws;
    float* wsA   = ws;                               // BATCH*NJ*12 = 147456 floats
    float* jtjs  = wsA + (size_t)BATCH * NJ * 12;    // NJ*33 = 792 (atomic-final)
    float* epre  = jtjs + NJ * 33;                   // NEXTRA*NJ*34 = 7344
    float* vtT   = epre + NEXTRA * NJ * EPN;         // 3*NV  = 20670
    float* sdT   = vtT + 3 * NV;                     // 30*NV = 206700
    float* lbswT = sdT + 30 * NV;                    // 24*NV = 165360

    // zero the atomic accumulator (ws is poisoned before each call)
    hipMemsetAsync(jtjs, 0, NJ * 33 * sizeof(float), stream);

    dim3 gT(VBLK, 3);
    transpose_kernel<<<gT, 256, 0, stream>>>(smpl_t, smil_t, sdirs, lbsw, msc,
                                             vtT, sdT, lbswT);

    dim3 gA(PCHUNK + NEXTRA, NJ);
    pre_kernel<<<gA, 256, 0, stream>>>(jreg, jre, vtT, sdT, lbswT, jtjs, epre);

    joints_kernel<<<BATCH, 64, 0, stream>>>(betas, body_pose, glob_or, transl,
                                            jtjs, epre, wsA, out);

    dim3 gC(VBLK, BATCH / BPB);
    lbs_kernel<<<gC, 256, 0, stream>>>(betas, transl, msc, smpl_t, smil_t, sdirs, lbsw, wsA, out);
}